// Round 3
// baseline (402.973 us; speedup 1.0000x reference)
//
#include <hip/hip_runtime.h>

// ---------------------------------------------------------------------------
// GALE_FA: FLARE low-rank self-attn + context cross-attn + gated mix.
// fp32 inputs/outputs; heavy compute as bf16 MFMA GEMMs with hi/lo splits on
// every softmax-logit operand. Deterministic (no atomics).
// Workspace fits in 209,266,688 B (round-0-proven footprint was 209,727,488).
// ---------------------------------------------------------------------------

typedef unsigned short u16;
typedef __attribute__((ext_vector_type(4))) float  f32x4;
typedef __attribute__((ext_vector_type(4))) u16    u16x4;
typedef __attribute__((ext_vector_type(8))) __bf16 bf16x8;

__device__ __forceinline__ float bf2f(u16 u) {
    return __uint_as_float(((unsigned)u) << 16);
}
__device__ __forceinline__ u16 f2bf(float f) {   // round-to-nearest-even
    unsigned u = __float_as_uint(f);
    u += 0x7fffu + ((u >> 16) & 1u);
    return (u16)(u >> 16);
}
__device__ __forceinline__ void gload16(const void* g, void* l) {
    __builtin_amdgcn_global_load_lds(
        (const __attribute__((address_space(1))) unsigned int*)g,
        (__attribute__((address_space(3))) unsigned int*)l, 16, 0, 0);
}

#define MASK_NONE 0x7fffffffu

// ---------------------------------------------------------------------------
// Generic MFMA GEMM core:  acc += sum_kk A[trow+r][(koffA+kk)&amask]
//                                       * B[tcol+c][(koffB+kk)&bmask]
// A: (rows x K) bf16 row-major, lda.  B: (cols x K) bf16 row-major ("B^T").
// BMxBN tile, 4 waves as WMW x WNW, BK=32, m97-style 2-barrier loop.
// ---------------------------------------------------------------------------
template<int BM, int BN, int WMW, int WNW>
__device__ __forceinline__ void gemm_core(
    const u16* __restrict__ A, int lda, unsigned amask, int koffA,
    const u16* __restrict__ Bm, int ldb, unsigned bmask, int koffB,
    int K, int trow, int tcol,
    u16* As, u16* Bs,
    f32x4 (&acc)[BM / WMW / 16][BN / WNW / 16])
{
    constexpr int FM = BM / WMW / 16;
    constexpr int FN = BN / WNW / 16;
    const int tid  = threadIdx.x;
    const int wid  = tid >> 6, lane = tid & 63;
    const int wm   = wid % WMW, wn = wid / WMW;
    const int wr   = wm * (BM / WMW), wc = wn * (BN / WNW);
    const int lrow = lane & 15, lk = (lane >> 4) * 8;

    for (int kt = 0; kt < K; kt += 32) {
        __syncthreads();
#pragma unroll
        for (int i = 0; i < BM / 64; i++) {           // stage A tile
            int c = i * 256 + tid;
            int row = c >> 2, kg = c & 3;
            unsigned kk = ((unsigned)(koffA + kt + kg * 8)) & amask;
            gload16(A + (size_t)(trow + row) * lda + kk, As + (size_t)c * 8);
        }
#pragma unroll
        for (int i = 0; i < BN / 64; i++) {           // stage B tile
            int c = i * 256 + tid;
            int col = c >> 2, kg = c & 3;
            unsigned kk = ((unsigned)(koffB + kt + kg * 8)) & bmask;
            gload16(Bm + (size_t)(tcol + col) * ldb + kk, Bs + (size_t)c * 8);
        }
        __syncthreads();

        bf16x8 af[FM], bfr[FN];
#pragma unroll
        for (int fm = 0; fm < FM; fm++)
            af[fm] = *(const bf16x8*)&As[(wr + fm * 16 + lrow) * 32 + lk];
#pragma unroll
        for (int fn = 0; fn < FN; fn++)
            bfr[fn] = *(const bf16x8*)&Bs[(wc + fn * 16 + lrow) * 32 + lk];
#pragma unroll
        for (int fm = 0; fm < FM; fm++)
#pragma unroll
            for (int fn = 0; fn < FN; fn++)
                acc[fm][fn] = __builtin_amdgcn_mfma_f32_16x16x32_bf16(
                    af[fm], bfr[fn], acc[fm][fn], 0, 0, 0);
    }
}

// ---------------------------------------------------------------------------
// Prep kernels (fp32 inputs)
// ---------------------------------------------------------------------------

// x -> xs = [xh | xl] bf16 per row (row stride 1024)
__global__ void prep_x(const float* __restrict__ x, u16* __restrict__ xs)
{
    int t = blockIdx.x * 256 + threadIdx.x;       // 2*16384*512/4
    int n = t >> 7, e4 = (t & 127) << 2;
    f32x4 v = *(const f32x4*)(x + (size_t)n * 512 + e4);
    u16x4 hi, lo;
#pragma unroll
    for (int j = 0; j < 4; j++) {
        u16 h = f2bf(v[j]);
        hi[j] = h;
        lo[j] = f2bf(v[j] - bf2f(h));
    }
    *(u16x4*)(xs + (size_t)n * 1024 + e4)       = hi;
    *(u16x4*)(xs + (size_t)n * 1024 + 512 + e4) = lo;
}

// Composed weights: CK=Wk@Wx_head, CQ=Wcq@Wx_head -> wKQ rows [Ch|Ch|Cl] (1536);
// CV=Wv@Wx_head -> wV bf16 (512x512).
__global__ void prep_w(const float* Wk, const float* Wcq, const float* Wv, const float* Wx,
                       u16* wKQ, u16* wV)
{
    int idx = blockIdx.x * 256 + threadIdx.x;     // 3*512*512
    int which = idx >> 18;
    int rem = idx & 262143;
    int c = rem >> 9, e = rem & 511;
    int h = c >> 6, d = c & 63;
    const float* W = which == 0 ? Wk : (which == 1 ? Wcq : Wv);
    float s = 0.f;
#pragma unroll 8
    for (int j = 0; j < 64; j++)
        s += W[d * 64 + j] * Wx[(h * 64 + j) * 512 + e];
    if (which == 2) { wV[(size_t)c * 512 + e] = f2bf(s); return; }
    int row = (which == 0) ? c : 512 + c;
    u16 hi = f2bf(s);
    wKQ[(size_t)row * 1536 + e]        = hi;
    wKQ[(size_t)row * 1536 + 512 + e]  = hi;
    wKQ[(size_t)row * 1536 + 1024 + e] = f2bf(s - bf2f(hi));
}

// Composed biases: biasKQ[0..511]=k-bias, [512..1023]=q-bias; biasV.
__global__ void prep_bias(const float* Wk, const float* Wcq, const float* Wv,
                          const float* bk, const float* bcq, const float* bv,
                          const float* bx, float* biasKQ, float* biasV)
{
    int t = blockIdx.x * 256 + threadIdx.x;       // 1536
    if (t < 1024) {
        const float* W  = (t < 512) ? Wk : Wcq;
        const float* bb = (t < 512) ? bk : bcq;
        int c = t & 511; int h = c >> 6, d = c & 63;
        float s = bb[d];
        for (int j = 0; j < 64; j++) s += W[d * 64 + j] * bx[h * 64 + j];
        biasKQ[t] = s;
    } else if (t < 1536) {
        int c = t - 1024; int h = c >> 6, d = c & 63;
        float s = bv[d];
        for (int j = 0; j < 64; j++) s += Wv[d * 64 + j] * bx[h * 64 + j];
        biasV[c] = s;
    }
}

// q_global -> qgs rows [qh|qh|ql] (8*64 x 192)
__global__ void prep_qg(const float* qg, u16* qgs)
{
    int t = blockIdx.x * 256 + threadIdx.x;       // 8*64*64
    int hm = t >> 6, d = t & 63;
    float v = qg[(size_t)hm * 64 + d];
    u16 hi = f2bf(v);
    qgs[(size_t)hm * 192 + d]        = hi;
    qgs[(size_t)hm * 192 + 64 + d]   = hi;
    qgs[(size_t)hm * 192 + 128 + d]  = f2bf(v - bf2f(hi));
}

// Wo -> bf16
__global__ void prep_wo(const float* Wo, u16* wo16)
{
    int t = blockIdx.x * 256 + threadIdx.x;       // 512*512
    wo16[t] = f2bf(Wo[t]);
}

// kc rows [kch|kch|kcl] (192) and vc fp32.
__global__ void prep_ctx(const float* ctx, const float* Wck, const float* bck,
                         const float* Wcv, const float* bcv, u16* kcB, float* vcf)
{
    int t = blockIdx.x * 256 + threadIdx.x;       // 16*64*64
    int bh = t >> 12, r = t & 4095;
    int s_ = r >> 6, d = r & 63;
    const float* crow = ctx + ((size_t)bh * 64 + s_) * 64;
    float kc = bck[d], vc = bcv[d];
#pragma unroll 8
    for (int e = 0; e < 64; e++) {
        float ce = crow[e];
        kc += ce * Wck[d * 64 + e];
        vc += ce * Wcv[d * 64 + e];
    }
    u16 hi = f2bf(kc);
    size_t base = ((size_t)bh * 64 + s_) * 192;
    kcB[base + d]        = hi;
    kcB[base + 64 + d]   = hi;
    kcB[base + 128 + d]  = f2bf(kc - bf2f(hi));
    vcf[((size_t)bh * 64 + s_) * 64 + d] = vc;
}

// ---------------------------------------------------------------------------
// G1a: [k,q] = xs @ wKQ^T (+bias), hi/lo split-store into SK/SQ.
// SK/SQ row n (stride 1024): per head h at h*128: [hi(64) | lo(64)]
// ---------------------------------------------------------------------------
__global__ __launch_bounds__(256, 2) void k_g1a(const u16* xs, const u16* wKQ,
                                                const float* biasKQ, u16* SK, u16* SQ)
{
    __shared__ u16 As[128 * 32], Bs[128 * 32];
    f32x4 acc[4][4] = {};
    int trow = blockIdx.y * 128, tcol = blockIdx.x * 128;
    gemm_core<128, 128, 2, 2>(xs, 1024, 1023u, 0, wKQ, 1536, MASK_NONE, 0,
                              1536, trow, tcol, As, Bs, acc);
    int tid = threadIdx.x, wid = tid >> 6, lane = tid & 63;
    int wr = (wid & 1) * 64, wc = (wid >> 1) * 64;
    int g = lane >> 4, li = lane & 15;
#pragma unroll
    for (int fm = 0; fm < 4; fm++)
#pragma unroll
        for (int fn = 0; fn < 4; fn++) {
            int col = tcol + wc + fn * 16 + li;
            float bias = biasKQ[col];
            u16* dst; int cc;
            if (col < 512) { cc = col; dst = SK; } else { cc = col - 512; dst = SQ; }
            int h = cc >> 6, d = cc & 63;
#pragma unroll
            for (int j = 0; j < 4; j++) {
                int row = trow + wr + fm * 16 + g * 4 + j;
                float v = acc[fm][fn][j] + bias;
                u16 hi = f2bf(v);
                size_t base = (size_t)row * 1024 + h * 128 + d;
                dst[base]      = hi;
                dst[base + 64] = f2bf(v - bf2f(hi));
            }
        }
}

// vT = CV @ bf16(x)^T (+row bias): vT[b][hd][n].  Reads fp32 x directly,
// register-staged f32->bf16 conversion into LDS (so XS can be reused).
__global__ __launch_bounds__(256, 2) void k_vt(const u16* wV, const float* x,
                                               const float* biasV, u16* vT)
{
    __shared__ u16 As[128 * 32], Bs[128 * 32];
    f32x4 acc[4][4] = {};
    int b = blockIdx.z;
    int trow = blockIdx.y * 128, tcol = blockIdx.x * 128;
    const float* xb = x + (size_t)b * 16384 * 512;
    int tid = threadIdx.x, wid = tid >> 6, lane = tid & 63;
    int wr = (wid & 1) * 64, wc = (wid >> 1) * 64;
    int lrow = lane & 15, lk = (lane >> 4) * 8;

    for (int kt = 0; kt < 512; kt += 32) {
        __syncthreads();
#pragma unroll
        for (int i = 0; i < 2; i++) {                 // stage A (wV bf16)
            int c = i * 256 + tid;
            int row = c >> 2, kg = c & 3;
            gload16(wV + (size_t)(trow + row) * 512 + kt + kg * 8, As + (size_t)c * 8);
        }
#pragma unroll
        for (int i = 0; i < 4; i++) {                 // stage B (x fp32 -> bf16)
            int c = (i * 256 + tid) * 4;
            int row = c >> 5, kk = c & 31;
            f32x4 v = *(const f32x4*)(xb + (size_t)(tcol + row) * 512 + kt + kk);
            u16x4 hv;
#pragma unroll
            for (int j = 0; j < 4; j++) hv[j] = f2bf(v[j]);
            *(u16x4*)(Bs + row * 32 + kk) = hv;
        }
        __syncthreads();

        bf16x8 af[4], bfr[4];
#pragma unroll
        for (int fm = 0; fm < 4; fm++)
            af[fm] = *(const bf16x8*)&As[(wr + fm * 16 + lrow) * 32 + lk];
#pragma unroll
        for (int fn = 0; fn < 4; fn++)
            bfr[fn] = *(const bf16x8*)&Bs[(wc + fn * 16 + lrow) * 32 + lk];
#pragma unroll
        for (int fm = 0; fm < 4; fm++)
#pragma unroll
            for (int fn = 0; fn < 4; fn++)
                acc[fm][fn] = __builtin_amdgcn_mfma_f32_16x16x32_bf16(
                    af[fm], bfr[fn], acc[fm][fn], 0, 0, 0);
    }

    int g = lane >> 4, li = lane & 15;
#pragma unroll
    for (int fm = 0; fm < 4; fm++)
#pragma unroll
        for (int fn = 0; fn < 4; fn++) {
            int col = tcol + wc + fn * 16 + li;
#pragma unroll
            for (int j = 0; j < 4; j++) {
                int a = trow + wr + fm * 16 + g * 4 + j;
                vT[((size_t)b * 512 + a) * 16384 + col] = f2bf(acc[fm][fn][j] + biasV[a]);
            }
        }
}

// S1: enc logits (K=192: qh*kh+qh*kl+ql*kh); fused exp -> P bf16 + partial dens.
__global__ __launch_bounds__(256, 2) void k_s1(const u16* qgs, const u16* SK,
                                               u16* P, float* denp)
{
    __shared__ u16 As[64 * 32], Bs[128 * 32];
    __shared__ float denL[4][64];
    f32x4 acc[4][2] = {};
    int bh = blockIdx.z, b = bh >> 3, h = bh & 7;
    int tcol = blockIdx.x * 128;
    gemm_core<64, 128, 1, 4>(qgs + (size_t)h * 12288, 192, MASK_NONE, 0,
                             SK + (size_t)b * 16384 * 1024 + h * 128, 1024, 127u, 0,
                             192, 0, tcol, As, Bs, acc);
    int tid = threadIdx.x, wid = tid >> 6, lane = tid & 63;
    int wc = wid * 32;
    int g = lane >> 4, li = lane & 15;
#pragma unroll
    for (int fm = 0; fm < 4; fm++)
#pragma unroll
        for (int j = 0; j < 4; j++) {
            int row = fm * 16 + g * 4 + j;                    // m
            float e0 = __expf(acc[fm][0][j]);
            float e1 = __expf(acc[fm][1][j]);
            size_t pb = (size_t)bh * 1048576 + (size_t)row * 16384 + tcol + wc;
            P[pb + li]      = f2bf(e0);
            P[pb + 16 + li] = f2bf(e1);
            float s = e0 + e1;
            s += __shfl_xor(s, 1); s += __shfl_xor(s, 2);
            s += __shfl_xor(s, 4); s += __shfl_xor(s, 8);
            if (li == 0) denL[wid][row] = s;
        }
    __syncthreads();
    if (tid < 64) {
        float d = denL[0][tid] + denL[1][tid] + denL[2][tid] + denL[3][tid];
        denp[(size_t)(bh * 64 + tid) * 128 + blockIdx.x] = d;
    }
}

__global__ void k_rden(const float* denp, float* den)
{
    int t = blockIdx.x * 256 + threadIdx.x;       // 1024
    if (t < 1024) {
        float s = 0.f;
        const float* p = denp + (size_t)t * 128;
        for (int i = 0; i < 128; i++) s += p[i];
        den[t] = s;
    }
}

// latent^T (unnormalized) split-K: latp[ch][bh][d][m] = sum_n vT[d][n] P[m][n]
__global__ __launch_bounds__(256, 2) void k_latT(const u16* vT, const u16* P, float* latp)
{
    __shared__ u16 As[64 * 32], Bs[64 * 32];
    f32x4 acc[2][2] = {};
    int ch = blockIdx.x, bh = blockIdx.z;
    int koff = ch * 2048;
    gemm_core<64, 64, 2, 2>(vT + (size_t)bh * 64 * 16384, 16384, MASK_NONE, koff,
                            P + (size_t)bh * 1048576, 16384, MASK_NONE, koff,
                            2048, 0, 0, As, Bs, acc);
    float* C = latp + ((size_t)ch * 16 + bh) * 4096;
    int tid = threadIdx.x, wid = tid >> 6, lane = tid & 63;
    int wr = (wid & 1) * 32, wc = (wid >> 1) * 32;
    int g = lane >> 4, li = lane & 15;
#pragma unroll
    for (int fm = 0; fm < 2; fm++)
#pragma unroll
        for (int fn = 0; fn < 2; fn++)
#pragma unroll
            for (int j = 0; j < 4; j++) {
                int row = wr + fm * 16 + g * 4 + j;   // d
                int col = wc + fn * 16 + li;          // m
                C[row * 64 + col] = acc[fm][fn][j];
            }
}

// finish latent (/den), sigmoid gate, build BT2[bh][d][0..63]=w*latT, [64..127]=(1-w)*vc^T
__global__ void k_latfin(const float* latp, const float* den, const float* vcf,
                         const float* smix, u16* BT2)
{
    int t = blockIdx.x * 256 + threadIdx.x;       // 16*64*64
    int bh = t >> 12, r = t & 4095;
    int d = r >> 6, m = r & 63;
    float w = 1.f / (1.f + __expf(-smix[0]));
    float s = 0.f;
    for (int c = 0; c < 8; c++) s += latp[((size_t)c * 16 + bh) * 4096 + r];
    float lat = s / den[bh * 64 + m];
    BT2[(size_t)bh * 8192 + d * 128 + m]      = f2bf(w * lat);
    BT2[(size_t)bh * 8192 + d * 128 + 64 + m] = f2bf((1.f - w) * vcf[((size_t)bh * 64 + m) * 64 + d]);
}

// S2 (dec logits) + S3 (cross logits), both K=192 hi/lo-exact, fused 64-wide
// softmax -> P12 bf16 [bh][n][p1(64)|p2(64)]
__global__ __launch_bounds__(256, 2) void k_s2s3(const u16* SK, const u16* SQ,
                                                 const u16* qgs, const u16* kcB, u16* P12)
{
    __shared__ u16 As[128 * 32], Bs[64 * 32];
    f32x4 acc1[2][4] = {}, acc2[2][4] = {};
    int bh = blockIdx.z, b = bh >> 3, h = bh & 7;
    int trow = blockIdx.y * 128;
    gemm_core<128, 64, 4, 1>(SK + (size_t)b * 16384 * 1024 + h * 128, 1024, 127u, 0,
                             qgs + (size_t)h * 12288, 192, MASK_NONE, 0,
                             192, trow, 0, As, Bs, acc1);
    gemm_core<128, 64, 4, 1>(SQ + (size_t)b * 16384 * 1024 + h * 128, 1024, 127u, 0,
                             kcB + (size_t)bh * 12288, 192, MASK_NONE, 0,
                             192, trow, 0, As, Bs, acc2);
    int tid = threadIdx.x, wid = tid >> 6, lane = tid & 63;
    int wr = wid * 32;
    int g = lane >> 4, li = lane & 15;
#pragma unroll
    for (int half = 0; half < 2; half++) {
        f32x4 (*ac)[4] = half ? acc2 : acc1;
#pragma unroll
        for (int fm = 0; fm < 2; fm++)
#pragma unroll
            for (int j = 0; j < 4; j++) {
                float e[4]; float s = 0.f;
#pragma unroll
                for (int fn = 0; fn < 4; fn++) { e[fn] = __expf(ac[fm][fn][j]); s += e[fn]; }
                s += __shfl_xor(s, 1); s += __shfl_xor(s, 2);
                s += __shfl_xor(s, 4); s += __shfl_xor(s, 8);
                float inv = 1.f / s;
                size_t row = trow + wr + fm * 16 + g * 4 + j;
                size_t base = ((size_t)bh * 16384 + row) * 128 + half * 64;
#pragma unroll
                for (int fn = 0; fn < 4; fn++)
                    P12[base + fn * 16 + li] = f2bf(e[fn] * inv);
            }
    }
}

// out_mid[b][n][h*64+d] = [p1|p2] @ BT2^T  (K=128)
__global__ __launch_bounds__(256, 2) void k_om(const u16* P12, const u16* BT2, u16* OM)
{
    __shared__ u16 As[128 * 32], Bs[64 * 32];
    f32x4 acc[2][4] = {};
    int bh = blockIdx.z, b = bh >> 3, h = bh & 7;
    int trow = blockIdx.y * 128;
    gemm_core<128, 64, 4, 1>(P12 + (size_t)bh * 16384 * 128, 128, MASK_NONE, 0,
                             BT2 + (size_t)bh * 8192, 128, MASK_NONE, 0,
                             128, trow, 0, As, Bs, acc);
    int tid = threadIdx.x, wid = tid >> 6, lane = tid & 63;
    int wr = wid * 32;
    int g = lane >> 4, li = lane & 15;
#pragma unroll
    for (int fm = 0; fm < 2; fm++)
#pragma unroll
        for (int fn = 0; fn < 4; fn++)
#pragma unroll
            for (int j = 0; j < 4; j++) {
                int row = trow + wr + fm * 16 + g * 4 + j;
                int col = fn * 16 + li;
                OM[((size_t)b * 16384 + row) * 512 + h * 64 + col] = f2bf(acc[fm][fn][j]);
            }
}

// final: out(fp32) = OM @ Wo^T + bo
__global__ __launch_bounds__(256, 2) void k_f(const u16* OM, const u16* wo16,
                                              const float* bo, float* out)
{
    __shared__ u16 As[128 * 32], Bs[128 * 32];
    f32x4 acc[4][4] = {};
    int trow = blockIdx.y * 128, tcol = blockIdx.x * 128;
    gemm_core<128, 128, 2, 2>(OM, 512, MASK_NONE, 0, wo16, 512, MASK_NONE, 0,
                              512, trow, tcol, As, Bs, acc);
    int tid = threadIdx.x, wid = tid >> 6, lane = tid & 63;
    int wr = (wid & 1) * 64, wc = (wid >> 1) * 64;
    int g = lane >> 4, li = lane & 15;
#pragma unroll
    for (int fm = 0; fm < 4; fm++)
#pragma unroll
        for (int fn = 0; fn < 4; fn++) {
            int col = tcol + wc + fn * 16 + li;
            float bias = bo[col];
#pragma unroll
            for (int j = 0; j < 4; j++) {
                int row = trow + wr + fm * 16 + g * 4 + j;
                out[(size_t)row * 512 + col] = acc[fm][fn][j] + bias;
            }
        }
}

// ---------------------------------------------------------------------------
// Workspace layout (bytes), total 209,266,688 (< proven-safe 209,727,488).
// Aliasing: XS dead after k_g1a (k_vt reads fp32 x directly); VT+P alias XS;
// P12 aliases VT+P (dead after k_latT); OM aliases SK (dead after k_s2s3).
// ---------------------------------------------------------------------------
static const size_t SK_OFF   = 0;            // u16 32768x1024   (67,108,864)
static const size_t SQ_OFF   = 67108864;     // u16 32768x1024   (67,108,864)
static const size_t XS_OFF   = 134217728;    // u16 32768x1024   (67,108,864) [dead after g1a]
static const size_t VT_OFF   = 134217728;    // u16 2x512x16384  (33,554,432) [alias XS lo]
static const size_t P_OFF    = 167772160;    // u16 16x64x16384  (33,554,432) [alias XS hi]
static const size_t P12_OFF  = 134217728;    // u16 16x16384x128 (67,108,864) [alias VT+P]
static const size_t OM_OFF   = 0;            // u16 32768x512    (33,554,432) [alias SK]
static const size_t WKQ_OFF  = 201326592;    // u16 1024x1536    (3,145,728)
static const size_t WV_OFF   = 204472320;    // u16 512x512      (524,288)
static const size_t WO_OFF   = 204996608;    // u16 512x512      (524,288)
static const size_t QGS_OFF  = 205520896;    // u16 512x192      (196,608)
static const size_t KCB_OFF  = 205717504;    // u16 1024x192     (393,216)
static const size_t VCF_OFF  = 206110720;    // f32 16x64x64     (262,144)
static const size_t BKQ_OFF  = 206372864;    // f32 1024         (4,096)
static const size_t BV_OFF   = 206376960;    // f32 512          (2,048)
static const size_t DENP_OFF = 206379008;    // f32 1024x128     (524,288)
static const size_t DEN_OFF  = 206903296;    // f32 1024         (4,096)
static const size_t LATP_OFF = 206907392;    // f32 8x16x64x64   (2,097,152)
static const size_t BT2_OFF  = 209004544;    // u16 16x64x128    (262,144)
// end: 209,266,688

extern "C" void kernel_launch(void* const* d_in, const int* in_sizes, int n_in,
                              void* d_out, int out_size, void* d_ws, size_t ws_size,
                              hipStream_t stream)
{
    const float* x    = (const float*)d_in[0];
    const float* ctx  = (const float*)d_in[1];
    const float* qg   = (const float*)d_in[2];
    const float* Wx   = (const float*)d_in[3];
    const float* bx   = (const float*)d_in[4];
    const float* Wk   = (const float*)d_in[5];
    const float* bk   = (const float*)d_in[6];
    const float* Wv   = (const float*)d_in[7];
    const float* bv   = (const float*)d_in[8];
    const float* Wcq  = (const float*)d_in[9];
    const float* bcq  = (const float*)d_in[10];
    const float* Wck  = (const float*)d_in[11];
    const float* bck  = (const float*)d_in[12];
    const float* Wcv  = (const float*)d_in[13];
    const float* bcv  = (const float*)d_in[14];
    const float* smix = (const float*)d_in[15];
    const float* Wo   = (const float*)d_in[16];
    const float* bo   = (const float*)d_in[17];

    char* ws = (char*)d_ws;
    u16*   xs    = (u16*)  (ws + XS_OFF);
    u16*   SK    = (u16*)  (ws + SK_OFF);
    u16*   SQ    = (u16*)  (ws + SQ_OFF);
    u16*   vT    = (u16*)  (ws + VT_OFF);
    u16*   P     = (u16*)  (ws + P_OFF);
    u16*   P12   = (u16*)  (ws + P12_OFF);
    u16*   OM    = (u16*)  (ws + OM_OFF);
    u16*   wKQ   = (u16*)  (ws + WKQ_OFF);
    u16*   wV    = (u16*)  (ws + WV_OFF);
    u16*   wo16  = (u16*)  (ws + WO_OFF);
    u16*   qgs   = (u16*)  (ws + QGS_OFF);
    u16*   kcB   = (u16*)  (ws + KCB_OFF);
    float* vcf   = (float*)(ws + VCF_OFF);
    float* biasKQ= (float*)(ws + BKQ_OFF);
    float* biasV = (float*)(ws + BV_OFF);
    float* denp  = (float*)(ws + DENP_OFF);
    float* den   = (float*)(ws + DEN_OFF);
    float* latp  = (float*)(ws + LATP_OFF);
    u16*   BT2   = (u16*)  (ws + BT2_OFF);

    prep_w   <<< 3072, 256, 0, stream>>>(Wk, Wcq, Wv, Wx, wKQ, wV);
    prep_bias<<<    6, 256, 0, stream>>>(Wk, Wcq, Wv, bk, bcq, bv, bx, biasKQ, biasV);
    prep_ctx <<<  256, 256, 0, stream>>>(ctx, Wck, bck, Wcv, bcv, kcB, vcf);
    prep_qg  <<<  128, 256, 0, stream>>>(qg, qgs);
    prep_wo  <<< 1024, 256, 0, stream>>>(Wo, wo16);
    prep_x   <<<16384, 256, 0, stream>>>(x, xs);

    k_g1a   <<<dim3(  8, 256, 1), 256, 0, stream>>>(xs, wKQ, biasKQ, SK, SQ);
    k_vt    <<<dim3(128,   4, 2), 256, 0, stream>>>(wV, x, biasV, vT);
    k_s1    <<<dim3(128,   1, 16), 256, 0, stream>>>(qgs, SK, P, denp);
    k_rden  <<<dim3(  4,   1, 1), 256, 0, stream>>>(denp, den);
    k_latT  <<<dim3(  8,   1, 16), 256, 0, stream>>>(vT, P, latp);
    k_latfin<<<dim3(256,   1, 1), 256, 0, stream>>>(latp, den, vcf, smix, BT2);
    k_s2s3  <<<dim3(  1, 128, 16), 256, 0, stream>>>(SK, SQ, qgs, kcB, P12);
    k_om    <<<dim3(  1, 128, 16), 256, 0, stream>>>(P12, BT2, OM);
    k_f     <<<dim3(  4, 256, 1), 256, 0, stream>>>(OM, wo16, bo, (float*)d_out);
}

// Round 4
// 373.174 us; speedup vs baseline: 1.0799x; 1.0799x over previous
//
#include <hip/hip_runtime.h>

// ---------------------------------------------------------------------------
// GALE_FA: FLARE low-rank self-attn + context cross-attn + gated mix.
// fp32 inputs/outputs; heavy compute as bf16 MFMA GEMMs with hi/lo splits on
// every softmax-logit operand. Deterministic (no atomics).
// R3: XCD-chunked block swizzles (g1a/vt/f), fused s2s3+om with LDS P12.
// ---------------------------------------------------------------------------

typedef unsigned short u16;
typedef __attribute__((ext_vector_type(4))) float  f32x4;
typedef __attribute__((ext_vector_type(4))) u16    u16x4;
typedef __attribute__((ext_vector_type(8))) __bf16 bf16x8;

__device__ __forceinline__ float bf2f(u16 u) {
    return __uint_as_float(((unsigned)u) << 16);
}
__device__ __forceinline__ u16 f2bf(float f) {   // round-to-nearest-even
    unsigned u = __float_as_uint(f);
    u += 0x7fffu + ((u >> 16) & 1u);
    return (u16)(u >> 16);
}
__device__ __forceinline__ void gload16(const void* g, void* l) {
    __builtin_amdgcn_global_load_lds(
        (const __attribute__((address_space(1))) unsigned int*)g,
        (__attribute__((address_space(3))) unsigned int*)l, 16, 0, 0);
}

#define MASK_NONE 0x7fffffffu

// ---------------------------------------------------------------------------
// Generic MFMA GEMM core (m97-style 2-barrier loop, BK=32).
// ---------------------------------------------------------------------------
template<int BM, int BN, int WMW, int WNW>
__device__ __forceinline__ void gemm_core(
    const u16* __restrict__ A, int lda, unsigned amask, int koffA,
    const u16* __restrict__ Bm, int ldb, unsigned bmask, int koffB,
    int K, int trow, int tcol,
    u16* As, u16* Bs,
    f32x4 (&acc)[BM / WMW / 16][BN / WNW / 16])
{
    constexpr int FM = BM / WMW / 16;
    constexpr int FN = BN / WNW / 16;
    const int tid  = threadIdx.x;
    const int wid  = tid >> 6, lane = tid & 63;
    const int wm   = wid % WMW, wn = wid / WMW;
    const int wr   = wm * (BM / WMW), wc = wn * (BN / WNW);
    const int lrow = lane & 15, lk = (lane >> 4) * 8;

    for (int kt = 0; kt < K; kt += 32) {
        __syncthreads();
#pragma unroll
        for (int i = 0; i < BM / 64; i++) {           // stage A tile
            int c = i * 256 + tid;
            int row = c >> 2, kg = c & 3;
            unsigned kk = ((unsigned)(koffA + kt + kg * 8)) & amask;
            gload16(A + (size_t)(trow + row) * lda + kk, As + (size_t)c * 8);
        }
#pragma unroll
        for (int i = 0; i < BN / 64; i++) {           // stage B tile
            int c = i * 256 + tid;
            int col = c >> 2, kg = c & 3;
            unsigned kk = ((unsigned)(koffB + kt + kg * 8)) & bmask;
            gload16(Bm + (size_t)(tcol + col) * ldb + kk, Bs + (size_t)c * 8);
        }
        __syncthreads();

        bf16x8 af[FM], bfr[FN];
#pragma unroll
        for (int fm = 0; fm < FM; fm++)
            af[fm] = *(const bf16x8*)&As[(wr + fm * 16 + lrow) * 32 + lk];
#pragma unroll
        for (int fn = 0; fn < FN; fn++)
            bfr[fn] = *(const bf16x8*)&Bs[(wc + fn * 16 + lrow) * 32 + lk];
#pragma unroll
        for (int fm = 0; fm < FM; fm++)
#pragma unroll
            for (int fn = 0; fn < FN; fn++)
                acc[fm][fn] = __builtin_amdgcn_mfma_f32_16x16x32_bf16(
                    af[fm], bfr[fn], acc[fm][fn], 0, 0, 0);
    }
}

// ---------------------------------------------------------------------------
// Prep kernels (fp32 inputs)
// ---------------------------------------------------------------------------

// x -> xs = [xh | xl] bf16 per row (row stride 1024)
__global__ void prep_x(const float* __restrict__ x, u16* __restrict__ xs)
{
    int t = blockIdx.x * 256 + threadIdx.x;       // 2*16384*512/4
    int n = t >> 7, e4 = (t & 127) << 2;
    f32x4 v = *(const f32x4*)(x + (size_t)n * 512 + e4);
    u16x4 hi, lo;
#pragma unroll
    for (int j = 0; j < 4; j++) {
        u16 h = f2bf(v[j]);
        hi[j] = h;
        lo[j] = f2bf(v[j] - bf2f(h));
    }
    *(u16x4*)(xs + (size_t)n * 1024 + e4)       = hi;
    *(u16x4*)(xs + (size_t)n * 1024 + 512 + e4) = lo;
}

// Composed weights: CK=Wk@Wx_head, CQ=Wcq@Wx_head -> wKQ rows [Ch|Ch|Cl] (1536);
// CV=Wv@Wx_head -> wV bf16 (512x512).
__global__ void prep_w(const float* Wk, const float* Wcq, const float* Wv, const float* Wx,
                       u16* wKQ, u16* wV)
{
    int idx = blockIdx.x * 256 + threadIdx.x;     // 3*512*512
    int which = idx >> 18;
    int rem = idx & 262143;
    int c = rem >> 9, e = rem & 511;
    int h = c >> 6, d = c & 63;
    const float* W = which == 0 ? Wk : (which == 1 ? Wcq : Wv);
    float s = 0.f;
#pragma unroll 8
    for (int j = 0; j < 64; j++)
        s += W[d * 64 + j] * Wx[(h * 64 + j) * 512 + e];
    if (which == 2) { wV[(size_t)c * 512 + e] = f2bf(s); return; }
    int row = (which == 0) ? c : 512 + c;
    u16 hi = f2bf(s);
    wKQ[(size_t)row * 1536 + e]        = hi;
    wKQ[(size_t)row * 1536 + 512 + e]  = hi;
    wKQ[(size_t)row * 1536 + 1024 + e] = f2bf(s - bf2f(hi));
}

// Composed biases: biasKQ[0..511]=k-bias, [512..1023]=q-bias; biasV.
__global__ void prep_bias(const float* Wk, const float* Wcq, const float* Wv,
                          const float* bk, const float* bcq, const float* bv,
                          const float* bx, float* biasKQ, float* biasV)
{
    int t = blockIdx.x * 256 + threadIdx.x;       // 1536
    if (t < 1024) {
        const float* W  = (t < 512) ? Wk : Wcq;
        const float* bb = (t < 512) ? bk : bcq;
        int c = t & 511; int h = c >> 6, d = c & 63;
        float s = bb[d];
        for (int j = 0; j < 64; j++) s += W[d * 64 + j] * bx[h * 64 + j];
        biasKQ[t] = s;
    } else if (t < 1536) {
        int c = t - 1024; int h = c >> 6, d = c & 63;
        float s = bv[d];
        for (int j = 0; j < 64; j++) s += Wv[d * 64 + j] * bx[h * 64 + j];
        biasV[c] = s;
    }
}

// q_global -> qgs rows [qh|qh|ql] (8*64 x 192)
__global__ void prep_qg(const float* qg, u16* qgs)
{
    int t = blockIdx.x * 256 + threadIdx.x;       // 8*64*64
    int hm = t >> 6, d = t & 63;
    float v = qg[(size_t)hm * 64 + d];
    u16 hi = f2bf(v);
    qgs[(size_t)hm * 192 + d]        = hi;
    qgs[(size_t)hm * 192 + 64 + d]   = hi;
    qgs[(size_t)hm * 192 + 128 + d]  = f2bf(v - bf2f(hi));
}

// Wo -> bf16
__global__ void prep_wo(const float* Wo, u16* wo16)
{
    int t = blockIdx.x * 256 + threadIdx.x;       // 512*512
    wo16[t] = f2bf(Wo[t]);
}

// kc rows [kch|kch|kcl] (192) and vc fp32.
__global__ void prep_ctx(const float* ctx, const float* Wck, const float* bck,
                         const float* Wcv, const float* bcv, u16* kcB, float* vcf)
{
    int t = blockIdx.x * 256 + threadIdx.x;       // 16*64*64
    int bh = t >> 12, r = t & 4095;
    int s_ = r >> 6, d = r & 63;
    const float* crow = ctx + ((size_t)bh * 64 + s_) * 64;
    float kc = bck[d], vc = bcv[d];
#pragma unroll 8
    for (int e = 0; e < 64; e++) {
        float ce = crow[e];
        kc += ce * Wck[d * 64 + e];
        vc += ce * Wcv[d * 64 + e];
    }
    u16 hi = f2bf(kc);
    size_t base = ((size_t)bh * 64 + s_) * 192;
    kcB[base + d]        = hi;
    kcB[base + 64 + d]   = hi;
    kcB[base + 128 + d]  = f2bf(kc - bf2f(hi));
    vcf[((size_t)bh * 64 + s_) * 64 + d] = vc;
}

// ---------------------------------------------------------------------------
// G1a: [k,q] = xs @ wKQ^T (+bias), hi/lo split-store into SK/SQ.
// XCD-chunked swizzle: each XCD owns contiguous trow range; tcol fastest.
// ---------------------------------------------------------------------------
__global__ __launch_bounds__(256, 2) void k_g1a(const u16* xs, const u16* wKQ,
                                                const float* biasKQ, u16* SK, u16* SQ)
{
    __shared__ u16 As[128 * 32], Bs[128 * 32];
    f32x4 acc[4][4] = {};
    int f = blockIdx.y * gridDim.x + blockIdx.x;       // 2048 blocks
    int w = (f & 7) * 256 + (f >> 3);                  // bijective (2048%8==0)
    int tcol = (w & 7) * 128, trow = (w >> 3) * 128;
    gemm_core<128, 128, 2, 2>(xs, 1024, 1023u, 0, wKQ, 1536, MASK_NONE, 0,
                              1536, trow, tcol, As, Bs, acc);
    int tid = threadIdx.x, wid = tid >> 6, lane = tid & 63;
    int wr = (wid & 1) * 64, wc = (wid >> 1) * 64;
    int g = lane >> 4, li = lane & 15;
#pragma unroll
    for (int fm = 0; fm < 4; fm++)
#pragma unroll
        for (int fn = 0; fn < 4; fn++) {
            int col = tcol + wc + fn * 16 + li;
            float bias = biasKQ[col];
            u16* dst; int cc;
            if (col < 512) { cc = col; dst = SK; } else { cc = col - 512; dst = SQ; }
            int h = cc >> 6, d = cc & 63;
#pragma unroll
            for (int j = 0; j < 4; j++) {
                int row = trow + wr + fm * 16 + g * 4 + j;
                float v = acc[fm][fn][j] + bias;
                u16 hi = f2bf(v);
                size_t base = (size_t)row * 1024 + h * 128 + d;
                dst[base]      = hi;
                dst[base + 64] = f2bf(v - bf2f(hi));
            }
        }
}

// vT = CV @ bf16(x)^T (+row bias): vT[b][hd][n].  Reads fp32 x directly,
// register-staged f32->bf16 into LDS.  Swizzle: trow fastest within XCD chunk.
__global__ __launch_bounds__(256, 2) void k_vt(const u16* wV, const float* x,
                                               const float* biasV, u16* vT)
{
    __shared__ u16 As[128 * 32], Bs[128 * 32];
    f32x4 acc[4][4] = {};
    int b = blockIdx.z;
    int f = blockIdx.y * gridDim.x + blockIdx.x;       // 512 blocks per z
    int w = (f & 7) * 64 + (f >> 3);
    int trow = (w & 3) * 128;
    int tcol = (w >> 2) * 128;
    const float* xb = x + (size_t)b * 16384 * 512;
    int tid = threadIdx.x, wid = tid >> 6, lane = tid & 63;
    int wr = (wid & 1) * 64, wc = (wid >> 1) * 64;
    int lrow = lane & 15, lk = (lane >> 4) * 8;

    for (int kt = 0; kt < 512; kt += 32) {
        __syncthreads();
#pragma unroll
        for (int i = 0; i < 2; i++) {                 // stage A (wV bf16)
            int c = i * 256 + tid;
            int row = c >> 2, kg = c & 3;
            gload16(wV + (size_t)(trow + row) * 512 + kt + kg * 8, As + (size_t)c * 8);
        }
#pragma unroll
        for (int i = 0; i < 4; i++) {                 // stage B (x fp32 -> bf16)
            int c = (i * 256 + tid) * 4;
            int row = c >> 5, kk = c & 31;
            f32x4 v = *(const f32x4*)(xb + (size_t)(tcol + row) * 512 + kt + kk);
            u16x4 hv;
#pragma unroll
            for (int j = 0; j < 4; j++) hv[j] = f2bf(v[j]);
            *(u16x4*)(Bs + row * 32 + kk) = hv;
        }
        __syncthreads();

        bf16x8 af[4], bfr[4];
#pragma unroll
        for (int fm = 0; fm < 4; fm++)
            af[fm] = *(const bf16x8*)&As[(wr + fm * 16 + lrow) * 32 + lk];
#pragma unroll
        for (int fn = 0; fn < 4; fn++)
            bfr[fn] = *(const bf16x8*)&Bs[(wc + fn * 16 + lrow) * 32 + lk];
#pragma unroll
        for (int fm = 0; fm < 4; fm++)
#pragma unroll
            for (int fn = 0; fn < 4; fn++)
                acc[fm][fn] = __builtin_amdgcn_mfma_f32_16x16x32_bf16(
                    af[fm], bfr[fn], acc[fm][fn], 0, 0, 0);
    }

    int g = lane >> 4, li = lane & 15;
#pragma unroll
    for (int fm = 0; fm < 4; fm++)
#pragma unroll
        for (int fn = 0; fn < 4; fn++) {
            int col = tcol + wc + fn * 16 + li;
#pragma unroll
            for (int j = 0; j < 4; j++) {
                int a = trow + wr + fm * 16 + g * 4 + j;
                vT[((size_t)b * 512 + a) * 16384 + col] = f2bf(acc[fm][fn][j] + biasV[a]);
            }
        }
}

// S1: enc logits (K=192); fused exp -> P bf16 + partial dens.
__global__ __launch_bounds__(256, 2) void k_s1(const u16* qgs, const u16* SK,
                                               u16* P, float* denp)
{
    __shared__ u16 As[64 * 32], Bs[128 * 32];
    __shared__ float denL[4][64];
    f32x4 acc[4][2] = {};
    int bh = blockIdx.z, b = bh >> 3, h = bh & 7;
    int tcol = blockIdx.x * 128;
    gemm_core<64, 128, 1, 4>(qgs + (size_t)h * 12288, 192, MASK_NONE, 0,
                             SK + (size_t)b * 16384 * 1024 + h * 128, 1024, 127u, 0,
                             192, 0, tcol, As, Bs, acc);
    int tid = threadIdx.x, wid = tid >> 6, lane = tid & 63;
    int wc = wid * 32;
    int g = lane >> 4, li = lane & 15;
#pragma unroll
    for (int fm = 0; fm < 4; fm++)
#pragma unroll
        for (int j = 0; j < 4; j++) {
            int row = fm * 16 + g * 4 + j;                    // m
            float e0 = __expf(acc[fm][0][j]);
            float e1 = __expf(acc[fm][1][j]);
            size_t pb = (size_t)bh * 1048576 + (size_t)row * 16384 + tcol + wc;
            P[pb + li]      = f2bf(e0);
            P[pb + 16 + li] = f2bf(e1);
            float s = e0 + e1;
            s += __shfl_xor(s, 1); s += __shfl_xor(s, 2);
            s += __shfl_xor(s, 4); s += __shfl_xor(s, 8);
            if (li == 0) denL[wid][row] = s;
        }
    __syncthreads();
    if (tid < 64) {
        float d = denL[0][tid] + denL[1][tid] + denL[2][tid] + denL[3][tid];
        denp[(size_t)(bh * 64 + tid) * 128 + blockIdx.x] = d;
    }
}

__global__ void k_rden(const float* denp, float* den)
{
    int t = blockIdx.x * 256 + threadIdx.x;       // 1024
    if (t < 1024) {
        float s = 0.f;
        const float* p = denp + (size_t)t * 128;
        for (int i = 0; i < 128; i++) s += p[i];
        den[t] = s;
    }
}

// latent^T (unnormalized) split-K: latp[ch][bh][d][m] = sum_n vT[d][n] P[m][n]
__global__ __launch_bounds__(256, 2) void k_latT(const u16* vT, const u16* P, float* latp)
{
    __shared__ u16 As[64 * 32], Bs[64 * 32];
    f32x4 acc[2][2] = {};
    int ch = blockIdx.x, bh = blockIdx.z;
    int koff = ch * 2048;
    gemm_core<64, 64, 2, 2>(vT + (size_t)bh * 64 * 16384, 16384, MASK_NONE, koff,
                            P + (size_t)bh * 1048576, 16384, MASK_NONE, koff,
                            2048, 0, 0, As, Bs, acc);
    float* C = latp + ((size_t)ch * 16 + bh) * 4096;
    int tid = threadIdx.x, wid = tid >> 6, lane = tid & 63;
    int wr = (wid & 1) * 32, wc = (wid >> 1) * 32;
    int g = lane >> 4, li = lane & 15;
#pragma unroll
    for (int fm = 0; fm < 2; fm++)
#pragma unroll
        for (int fn = 0; fn < 2; fn++)
#pragma unroll
            for (int j = 0; j < 4; j++) {
                int row = wr + fm * 16 + g * 4 + j;   // d
                int col = wc + fn * 16 + li;          // m
                C[row * 64 + col] = acc[fm][fn][j];
            }
}

// finish latent (/den), sigmoid gate, build BT2[bh][d][0..63]=w*latT, [64..127]=(1-w)*vc^T
__global__ void k_latfin(const float* latp, const float* den, const float* vcf,
                         const float* smix, u16* BT2)
{
    int t = blockIdx.x * 256 + threadIdx.x;       // 16*64*64
    int bh = t >> 12, r = t & 4095;
    int d = r >> 6, m = r & 63;
    float w = 1.f / (1.f + __expf(-smix[0]));
    float s = 0.f;
    for (int c = 0; c < 8; c++) s += latp[((size_t)c * 16 + bh) * 4096 + r];
    float lat = s / den[bh * 64 + m];
    BT2[(size_t)bh * 8192 + d * 128 + m]      = f2bf(w * lat);
    BT2[(size_t)bh * 8192 + d * 128 + 64 + m] = f2bf((1.f - w) * vcf[((size_t)bh * 64 + m) * 64 + d]);
}

// ---------------------------------------------------------------------------
// Fused S2+S3+OM: dec/cross logits (K=192 each, hi/lo-exact) -> fused 64-wide
// softmax -> P12 in LDS (XOR-swizzled) -> out_mid GEMM (K=128) vs BT2 (LDS).
// Writes OM (which aliases VT region, dead after k_latT).
// ---------------------------------------------------------------------------
__global__ __launch_bounds__(256, 2) void k_s2s3om(const u16* SK, const u16* SQ,
                                                   const u16* qgs, const u16* kcB,
                                                   const u16* BT2, u16* OM)
{
    __shared__ u16 As[128 * 32], Bs[64 * 32];
    __shared__ u16 P12L[128 * 128];     // [row][col^((row&7)<<3)]
    __shared__ u16 BT2s[64 * 128];      // [d][k^((d&7)<<3)]
    f32x4 acc1[2][4] = {}, acc2[2][4] = {};
    int bh = blockIdx.z, b = bh >> 3, h = bh & 7;
    int trow = blockIdx.y * 128;
    int tid = threadIdx.x, wid = tid >> 6, lane = tid & 63;

    // prefetch BT2 into LDS: linear dest + inverse-swizzled source (rule 21)
    const u16* BT2g = BT2 + (size_t)bh * 8192;
#pragma unroll
    for (int i = 0; i < 4; i++) {
        int c = i * 256 + tid;
        int row = c >> 4, kg = c & 15;
        gload16(BT2g + row * 128 + ((kg * 8) ^ ((row & 7) << 3)), BT2s + (size_t)c * 8);
    }

    gemm_core<128, 64, 4, 1>(SK + (size_t)b * 16384 * 1024 + h * 128, 1024, 127u, 0,
                             qgs + (size_t)h * 12288, 192, MASK_NONE, 0,
                             192, trow, 0, As, Bs, acc1);
    gemm_core<128, 64, 4, 1>(SQ + (size_t)b * 16384 * 1024 + h * 128, 1024, 127u, 0,
                             kcB + (size_t)bh * 12288, 192, MASK_NONE, 0,
                             192, trow, 0, As, Bs, acc2);

    int wr = wid * 32;
    int g = lane >> 4, li = lane & 15;
#pragma unroll
    for (int half = 0; half < 2; half++) {
        f32x4 (*ac)[4] = half ? acc2 : acc1;
#pragma unroll
        for (int fm = 0; fm < 2; fm++)
#pragma unroll
            for (int j = 0; j < 4; j++) {
                float e[4]; float s = 0.f;
#pragma unroll
                for (int fn = 0; fn < 4; fn++) { e[fn] = __expf(ac[fm][fn][j]); s += e[fn]; }
                s += __shfl_xor(s, 1); s += __shfl_xor(s, 2);
                s += __shfl_xor(s, 4); s += __shfl_xor(s, 8);
                float inv = 1.f / s;
                int rloc = wr + fm * 16 + g * 4 + j;
#pragma unroll
                for (int fn = 0; fn < 4; fn++) {
                    int colw = half * 64 + fn * 16 + li;
                    P12L[rloc * 128 + (colw ^ ((rloc & 7) << 3))] = f2bf(e[fn] * inv);
                }
            }
    }
    __syncthreads();

    // out_mid: OM[row][h*64+c] = sum_k P12[row][k] * BT2[c][k]
    f32x4 oacc[2][4] = {};
    int lrow = lane & 15, lk = (lane >> 4) * 8;
#pragma unroll
    for (int kt = 0; kt < 128; kt += 32) {
        bf16x8 af[2], bfr[4];
#pragma unroll
        for (int fm = 0; fm < 2; fm++) {
            int r = wr + fm * 16 + lrow;
            af[fm] = *(const bf16x8*)&P12L[r * 128 + ((kt + lk) ^ ((r & 7) << 3))];
        }
#pragma unroll
        for (int fn = 0; fn < 4; fn++) {
            int c2 = fn * 16 + lrow;
            bfr[fn] = *(const bf16x8*)&BT2s[c2 * 128 + ((kt + lk) ^ ((c2 & 7) << 3))];
        }
#pragma unroll
        for (int fm = 0; fm < 2; fm++)
#pragma unroll
            for (int fn = 0; fn < 4; fn++)
                oacc[fm][fn] = __builtin_amdgcn_mfma_f32_16x16x32_bf16(
                    af[fm], bfr[fn], oacc[fm][fn], 0, 0, 0);
    }
#pragma unroll
    for (int fm = 0; fm < 2; fm++)
#pragma unroll
        for (int fn = 0; fn < 4; fn++)
#pragma unroll
            for (int j = 0; j < 4; j++) {
                int row = trow + wr + fm * 16 + g * 4 + j;
                int col = fn * 16 + li;
                OM[((size_t)b * 16384 + row) * 512 + h * 64 + col] = f2bf(oacc[fm][fn][j]);
            }
}

// final: out(fp32) = OM @ Wo^T + bo.  Swizzle: tcol fastest within XCD chunk.
__global__ __launch_bounds__(256, 2) void k_f(const u16* OM, const u16* wo16,
                                              const float* bo, float* out)
{
    __shared__ u16 As[128 * 32], Bs[128 * 32];
    f32x4 acc[4][4] = {};
    int f = blockIdx.y * gridDim.x + blockIdx.x;       // 1024 blocks
    int w = (f & 7) * 128 + (f >> 3);
    int tcol = (w & 3) * 128, trow = (w >> 2) * 128;
    gemm_core<128, 128, 2, 2>(OM, 512, MASK_NONE, 0, wo16, 512, MASK_NONE, 0,
                              512, trow, tcol, As, Bs, acc);
    int tid = threadIdx.x, wid = tid >> 6, lane = tid & 63;
    int wr = (wid & 1) * 64, wc = (wid >> 1) * 64;
    int g = lane >> 4, li = lane & 15;
#pragma unroll
    for (int fm = 0; fm < 4; fm++)
#pragma unroll
        for (int fn = 0; fn < 4; fn++) {
            int col = tcol + wc + fn * 16 + li;
            float bias = bo[col];
#pragma unroll
            for (int j = 0; j < 4; j++) {
                int row = trow + wr + fm * 16 + g * 4 + j;
                out[(size_t)row * 512 + col] = acc[fm][fn][j] + bias;
            }
        }
}

// ---------------------------------------------------------------------------
// Workspace layout (bytes), total 209,266,688.
// Aliasing: XS dead after k_g1a; VT+P alias XS; OM aliases VT (dead after
// k_latT; s2s3om runs after latfin).  SK/SQ live until s2s3om completes.
// ---------------------------------------------------------------------------
static const size_t SK_OFF   = 0;            // u16 32768x1024   (67,108,864)
static const size_t SQ_OFF   = 67108864;     // u16 32768x1024   (67,108,864)
static const size_t XS_OFF   = 134217728;    // u16 32768x1024   (67,108,864) [dead after g1a]
static const size_t VT_OFF   = 134217728;    // u16 2x512x16384  (33,554,432) [alias XS lo]
static const size_t P_OFF    = 167772160;    // u16 16x64x16384  (33,554,432) [alias XS hi]
static const size_t OM_OFF   = 134217728;    // u16 32768x512    (33,554,432) [alias VT]
static const size_t WKQ_OFF  = 201326592;    // u16 1024x1536    (3,145,728)
static const size_t WV_OFF   = 204472320;    // u16 512x512      (524,288)
static const size_t WO_OFF   = 204996608;    // u16 512x512      (524,288)
static const size_t QGS_OFF  = 205520896;    // u16 512x192      (196,608)
static const size_t KCB_OFF  = 205717504;    // u16 1024x192     (393,216)
static const size_t VCF_OFF  = 206110720;    // f32 16x64x64     (262,144)
static const size_t BKQ_OFF  = 206372864;    // f32 1024         (4,096)
static const size_t BV_OFF   = 206376960;    // f32 512          (2,048)
static const size_t DENP_OFF = 206379008;    // f32 1024x128     (524,288)
static const size_t DEN_OFF  = 206903296;    // f32 1024         (4,096)
static const size_t LATP_OFF = 206907392;    // f32 8x16x64x64   (2,097,152)
static const size_t BT2_OFF  = 209004544;    // u16 16x64x128    (262,144)
// end: 209,266,688

extern "C" void kernel_launch(void* const* d_in, const int* in_sizes, int n_in,
                              void* d_out, int out_size, void* d_ws, size_t ws_size,
                              hipStream_t stream)
{
    const float* x    = (const float*)d_in[0];
    const float* ctx  = (const float*)d_in[1];
    const float* qg   = (const float*)d_in[2];
    const float* Wx   = (const float*)d_in[3];
    const float* bx   = (const float*)d_in[4];
    const float* Wk   = (const float*)d_in[5];
    const float* bk   = (const float*)d_in[6];
    const float* Wv   = (const float*)d_in[7];
    const float* bv   = (const float*)d_in[8];
    const float* Wcq  = (const float*)d_in[9];
    const float* bcq  = (const float*)d_in[10];
    const float* Wck  = (const float*)d_in[11];
    const float* bck  = (const float*)d_in[12];
    const float* Wcv  = (const float*)d_in[13];
    const float* bcv  = (const float*)d_in[14];
    const float* smix = (const float*)d_in[15];
    const float* Wo   = (const float*)d_in[16];
    const float* bo   = (const float*)d_in[17];

    char* ws = (char*)d_ws;
    u16*   xs    = (u16*)  (ws + XS_OFF);
    u16*   SK    = (u16*)  (ws + SK_OFF);
    u16*   SQ    = (u16*)  (ws + SQ_OFF);
    u16*   vT    = (u16*)  (ws + VT_OFF);
    u16*   P     = (u16*)  (ws + P_OFF);
    u16*   OM    = (u16*)  (ws + OM_OFF);
    u16*   wKQ   = (u16*)  (ws + WKQ_OFF);
    u16*   wV    = (u16*)  (ws + WV_OFF);
    u16*   wo16  = (u16*)  (ws + WO_OFF);
    u16*   qgs   = (u16*)  (ws + QGS_OFF);
    u16*   kcB   = (u16*)  (ws + KCB_OFF);
    float* vcf   = (float*)(ws + VCF_OFF);
    float* biasKQ= (float*)(ws + BKQ_OFF);
    float* biasV = (float*)(ws + BV_OFF);
    float* denp  = (float*)(ws + DENP_OFF);
    float* den   = (float*)(ws + DEN_OFF);
    float* latp  = (float*)(ws + LATP_OFF);
    u16*   BT2   = (u16*)  (ws + BT2_OFF);

    prep_w   <<< 3072, 256, 0, stream>>>(Wk, Wcq, Wv, Wx, wKQ, wV);
    prep_bias<<<    6, 256, 0, stream>>>(Wk, Wcq, Wv, bk, bcq, bv, bx, biasKQ, biasV);
    prep_ctx <<<  256, 256, 0, stream>>>(ctx, Wck, bck, Wcv, bcv, kcB, vcf);
    prep_qg  <<<  128, 256, 0, stream>>>(qg, qgs);
    prep_wo  <<< 1024, 256, 0, stream>>>(Wo, wo16);
    prep_x   <<<16384, 256, 0, stream>>>(x, xs);

    k_g1a   <<<dim3(  8, 256, 1), 256, 0, stream>>>(xs, wKQ, biasKQ, SK, SQ);
    k_vt    <<<dim3(128,   4, 2), 256, 0, stream>>>(wV, x, biasV, vT);
    k_s1    <<<dim3(128,   1, 16), 256, 0, stream>>>(qgs, SK, P, denp);
    k_rden  <<<dim3(  4,   1, 1), 256, 0, stream>>>(denp, den);
    k_latT  <<<dim3(  8,   1, 16), 256, 0, stream>>>(vT, P, latp);
    k_latfin<<<dim3(256,   1, 1), 256, 0, stream>>>(latp, den, vcf, smix, BT2);
    k_s2s3om<<<dim3(  1, 128, 16), 256, 0, stream>>>(SK, SQ, qgs, kcB, BT2, OM);
    k_f     <<<dim3(  4, 256, 1), 256, 0, stream>>>(OM, wo16, bo, (float*)d_out);
}